// Round 17
// baseline (440.149 us; speedup 1.0000x reference)
//
#include <hip/hip_runtime.h>
#include <math.h>

#define SEQ   2048
#define NH    8
#define DH    64          // p
#define DS    16          // n
#define NBH   512         // BATCH * NH
#define OUTBH 1024        // DH * DS
#define TT    32          // timesteps per staged tile
#define XTF   (TT * DH)   // 2048 floats (8 KB)
#define BTF   (TT * DS)   // 512 floats  (2 KB)
#define BUFF  (XTF + BTF) // 2560 floats (10 KB)
#define RS    20          // epilogue row stride (floats): 16B-aligned, spread banks
#define WST   (64 * RS)   // per-wave reduce tile (1280 floats) -> 4*WST == 2*BUFF

typedef float f4 __attribute__((ext_vector_type(4)));
#define AS1 __attribute__((address_space(1)))
#define AS3 __attribute__((address_space(3)))

// Stage one 32-t tile: X 8 KB as 8 linear 1-KB ops (chunk c = t 4c..4c+3),
// B 2 KB as 2 linear 1-KB ops (16 t each). Waves: X chunks {w, w+4}; B by
// waves 0,1. LDS layout linear: X [32][64], B [32][16].
__device__ __forceinline__ void stage_tile(const float* __restrict__ Xrow,
                                           const float* __restrict__ Brow,
                                           float* buf, int tb, int wave, int lane)
{
#pragma unroll
    for (int r = 0; r < 2; ++r) {
        const int c = wave + r * 4;
        const float* g = Xrow + (size_t)(tb + c * 4 + (lane >> 4)) * (NH * DH)
                              + (lane & 15) * 4;
        __builtin_amdgcn_global_load_lds((const AS1 void*)g,
                                         (AS3 void*)(buf + c * 256), 16, 0, 0);
    }
    if (wave < 2) {
        const float* g = Brow + (size_t)(tb + wave * 16 + (lane >> 2)) * (NH * DS)
                              + (lane & 3) * 4;
        __builtin_amdgcn_global_load_lds((const AS1 void*)g,
                                         (AS3 void*)(buf + XTF + wave * 256), 16, 0, 0);
    }
}

// One block per (segment, b, h); 4 waves. Per 32-t tile, wave w computes
// 4-t groups {2w, 2w+1}. Lane (tg=lane>>4, pg=lane&15) handles t = group*4+tg,
// owns p-quad pg x ALL 16 n: f4 acc[4][4]. X read: ONE stride-1 ds_read_b128
// per 4 t; B: 4-addr broadcast b128; w: broadcast b32. Epilogue: tg-butterfly
// within wave, then cross-wave LDS reduce (this was MISSING in R16 -> race).
__global__ __launch_bounds__(256, 4)
void ssd_state_tdense(const float* __restrict__ Xg,
                      const float* __restrict__ Ag,
                      const float* __restrict__ Bg,
                      float* __restrict__ dst,
                      int seglen)
{
    extern __shared__ float sm[];
    float* wseg  = sm;              // [seglen] weights
    float* stage = sm + seglen;     // [2][BUFF]; later 4 x WST reduce tiles

    const int tid = threadIdx.x;
    const int bid = blockIdx.x;
    const int bh  = bid & (NBH - 1);
    const int g   = bid >> 9;       // log2(NBH) = 9
    const int b   = bh >> 3;
    const int h   = bh & 7;
    const int t0  = g * seglen;

    // ---------------- phase 1: wseg[t] = exp(sum_{s>t} A[b,s,h]) ----------------
    const float* Ab = Ag + (size_t)b * SEQ * NH + h;
    {
        float a[8];
#pragma unroll
        for (int k = 0; k < 8; ++k)
            a[k] = Ab[(size_t)(tid * 8 + k) * NH];
        float tot = 0.f;
#pragma unroll
        for (int k = 0; k < 8; ++k) tot += a[k];
        stage[tid] = tot;           // scan scratch aliases staging buffer
        __syncthreads();
        for (int off = 1; off < 256; off <<= 1) {
            float v = stage[tid];
            float u = (tid + off < 256) ? stage[tid + off] : 0.f;
            __syncthreads();
            stage[tid] = v + u;
            __syncthreads();
        }
        float run = (tid < 255) ? stage[tid + 1] : 0.f;   // sum s >= (tid+1)*8
#pragma unroll
        for (int k = 7; k >= 0; --k) {
            int t = tid * 8 + k;
            if (t >= t0 && t < t0 + seglen)
                wseg[t - t0] = expf(run);
            run += a[k];
        }
        __syncthreads();   // wseg ready; scan scratch dead
    }

    // ---------------- phase 2: t-dense staged outer-product ---------------------
    const int wave = tid >> 6;
    const int lane = tid & 63;
    const int tg = lane >> 4;       // 0..3 : t within 4-t group
    const int pg = lane & 15;       // 0..15: p-quad

    const float* Xrow = Xg + (((size_t)b * SEQ + t0) * NH + h) * DH;
    const float* Brow = Bg + (((size_t)b * SEQ + t0) * NH + h) * DS;
    const int NTILE = seglen / TT;

    f4 acc[4][4];                   // [i = p offset within quad][q = n quad]
#pragma unroll
    for (int i = 0; i < 4; ++i)
#pragma unroll
        for (int q = 0; q < 4; ++q) acc[i][q] = (f4)0.f;

    int cur = 0;
    stage_tile(Xrow, Brow, stage, 0, wave, lane);
    __syncthreads();   // tile 0 landed (compiler drains vmcnt before barrier)

#pragma unroll 1
    for (int s = 0; s < NTILE; ++s) {
        if (s + 1 < NTILE)
            stage_tile(Xrow, Brow, stage + (cur ^ 1) * BUFF, (s + 1) * TT, wave, lane);

        const float* Xb = stage + cur * BUFF;
        const float* Bb = Xb + XTF;
        const float* wp = wseg + s * TT;
#pragma unroll
        for (int r = 0; r < 2; ++r) {
            const int tl = (wave * 2 + r) * 4 + tg;          // t within tile
            f4 xv = *(const f4*)&Xb[tl * DH + pg * 4];       // 1 stride-1 b128 / 4t
            float wv = wp[tl];
            f4 xw = xv * wv;
#pragma unroll
            for (int q = 0; q < 4; ++q) {
                f4 bq = *(const f4*)&Bb[tl * DS + q * 4];    // 4-addr broadcast
                acc[0][q] += xw.x * bq;
                acc[1][q] += xw.y * bq;
                acc[2][q] += xw.z * bq;
                acc[3][q] += xw.w * bq;
            }
        }
        __syncthreads();   // next tile landed; cur reads done before re-stage
        cur ^= 1;
    }

    // ---------------- phase 3: tg-butterfly, cross-wave LDS reduce, store --------
#pragma unroll
    for (int i = 0; i < 4; ++i)
#pragma unroll
        for (int q = 0; q < 4; ++q) {
            f4 v = acc[i][q];
            v.x += __shfl_xor(v.x, 16); v.y += __shfl_xor(v.y, 16);
            v.z += __shfl_xor(v.z, 16); v.w += __shfl_xor(v.w, 16);
            v.x += __shfl_xor(v.x, 32); v.y += __shfl_xor(v.y, 32);
            v.z += __shfl_xor(v.z, 32); v.w += __shfl_xor(v.w, 32);
            acc[i][q] = v;
        }
    // each wave writes its reduced tile (row p = pg*4+tg via static select);
    // staging area is dead after the final loop barrier -> alias as red[4][WST]
    float* red = stage;
    {
        float* rw = red + wave * WST;
#pragma unroll
        for (int q = 0; q < 4; ++q) {
            f4 r01 = (tg & 1) ? acc[1][q] : acc[0][q];
            f4 r23 = (tg & 1) ? acc[3][q] : acc[2][q];
            f4 v   = (tg & 2) ? r23 : r01;
            *(f4*)&rw[(pg * 4 + tg) * RS + q * 4] = v;
        }
    }
    __syncthreads();
    {
        const int e = tid * 4;
        const int r = e >> 4;        // p row
        const int c = e & 15;        // n col base
        const float* rp = red + r * RS + c;
        f4 s0 = *(const f4*)(rp);
        f4 s1 = *(const f4*)(rp + WST);
        f4 s2 = *(const f4*)(rp + 2 * WST);
        f4 s3 = *(const f4*)(rp + 3 * WST);
        f4 sv = (s0 + s1) + (s2 + s3);
        *(f4*)(dst + (size_t)bid * OUTBH + e) = sv;
    }
}

// Sum the NSEG=4 segment partials into the final output.
__global__ __launch_bounds__(256)
void seg_reduce4(const float* __restrict__ part, float* __restrict__ out)
{
    int i = blockIdx.x * 256 + threadIdx.x;
    size_t o = (size_t)i * 4;
    f4 s = (f4)0.f;
#pragma unroll
    for (int g2 = 0; g2 < 4; ++g2)
        s += *(const f4*)(part + (size_t)g2 * NBH * OUTBH + o);
    *(f4*)(out + o) = s;
}

extern "C" void kernel_launch(void* const* d_in, const int* in_sizes, int n_in,
                              void* d_out, int out_size, void* d_ws, size_t ws_size,
                              hipStream_t stream)
{
    const float* X  = (const float*)d_in[0];
    const float* A  = (const float*)d_in[1];
    const float* Bm = (const float*)d_in[2];
    // d_in[3] (C) is unused by the reference output.
    float* out = (float*)d_out;

    const size_t need = (size_t)4 * NBH * OUTBH * sizeof(float);  // 8 MB
    const int nseg   = (d_ws && ws_size >= need) ? 4 : 1;
    const int seglen = SEQ / nseg;
    float* dst = (nseg == 4) ? (float*)d_ws : out;
    const size_t lds = (size_t)(seglen + 2 * BUFF) * sizeof(float);  // 2*BUFF == 4*WST

    ssd_state_tdense<<<dim3(nseg * NBH), dim3(256), lds, stream>>>(X, A, Bm, dst, seglen);
    if (nseg == 4)
        seg_reduce4<<<dim3((NBH * OUTBH) / 1024), dim3(256), 0, stream>>>((const float*)d_ws, out);
}

// Round 18
// 86.799 us; speedup vs baseline: 5.0709x; 5.0709x over previous
//
#include <hip/hip_runtime.h>
#include <math.h>

#define SEQ   2048
#define NH    8
#define DH    64          // p
#define DS    16          // n
#define NBH   512         // BATCH * NH
#define OUTBH 1024        // DH * DS
#define TT    32          // timesteps per staged tile
#define XTF   (TT * DH)   // 2048 floats (8 KB)
#define BTF   (TT * DS)   // 512 floats  (2 KB)
#define BUFF  (XTF + BTF) // 2560 floats (10 KB)
#define RS    20          // epilogue row stride (floats): 16B-aligned, spread banks
#define WST   (64 * RS)   // per-wave reduce tile (1280 floats) -> 4*WST == 2*BUFF

typedef float f4 __attribute__((ext_vector_type(4)));
#define AS1 __attribute__((address_space(1)))
#define AS3 __attribute__((address_space(3)))

// Stage one 32-t tile: X 8 KB as 8 linear 1-KB ops (chunk c = t 4c..4c+3),
// B 2 KB as 2 linear 1-KB ops (16 t each). Waves: X chunks {w, w+4}; B by
// waves 0,1. LDS layout linear: X [32][64], B [32][16].
__device__ __forceinline__ void stage_tile(const float* __restrict__ Xrow,
                                           const float* __restrict__ Brow,
                                           float* buf, int tb, int wave, int lane)
{
#pragma unroll
    for (int r = 0; r < 2; ++r) {
        const int c = wave + r * 4;
        const float* g = Xrow + (size_t)(tb + c * 4 + (lane >> 4)) * (NH * DH)
                              + (lane & 15) * 4;
        __builtin_amdgcn_global_load_lds((const AS1 void*)g,
                                         (AS3 void*)(buf + c * 256), 16, 0, 0);
    }
    if (wave < 2) {
        const float* g = Brow + (size_t)(tb + wave * 16 + (lane >> 2)) * (NH * DS)
                              + (lane & 3) * 4;
        __builtin_amdgcn_global_load_lds((const AS1 void*)g,
                                         (AS3 void*)(buf + XTF + wave * 256), 16, 0, 0);
    }
}

__device__ __forceinline__ f4 bfly(f4 v)
{
    v.x += __shfl_xor(v.x, 16); v.y += __shfl_xor(v.y, 16);
    v.z += __shfl_xor(v.z, 16); v.w += __shfl_xor(v.w, 16);
    v.x += __shfl_xor(v.x, 32); v.y += __shfl_xor(v.y, 32);
    v.z += __shfl_xor(v.z, 32); v.w += __shfl_xor(v.w, 32);
    return v;
}

// One block per (segment, b, h); 4 waves. Per 32-t tile, wave w computes
// 4-t groups {2w, 2w+1}. Lane (tg=lane>>4, pg=lane&15) handles t = group*4+tg,
// owns p-quad pg x ALL 16 n. Accumulator: 16 NAMED f4 registers (a00..a33) —
// named scalars cannot be scratch-demoted (R17's f4 acc[4][4] array spilled:
// WRITE_SIZE 2 GB). X read: ONE stride-1 ds_read_b128 per 4 t.
__global__ __launch_bounds__(256, 4)
void ssd_state_tdense(const float* __restrict__ Xg,
                      const float* __restrict__ Ag,
                      const float* __restrict__ Bg,
                      float* __restrict__ dst,
                      int seglen)
{
    extern __shared__ float sm[];
    float* wseg  = sm;              // [seglen] weights
    float* stage = sm + seglen;     // [2][BUFF]; later 4 x WST reduce tiles

    const int tid = threadIdx.x;
    const int bid = blockIdx.x;
    const int bh  = bid & (NBH - 1);
    const int g   = bid >> 9;       // log2(NBH) = 9
    const int b   = bh >> 3;
    const int h   = bh & 7;
    const int t0  = g * seglen;

    // ---------------- phase 1: wseg[t] = exp(sum_{s>t} A[b,s,h]) ----------------
    const float* Ab = Ag + (size_t)b * SEQ * NH + h;
    {
        float a[8];
#pragma unroll
        for (int k = 0; k < 8; ++k)
            a[k] = Ab[(size_t)(tid * 8 + k) * NH];
        float tot = 0.f;
#pragma unroll
        for (int k = 0; k < 8; ++k) tot += a[k];
        stage[tid] = tot;           // scan scratch aliases staging buffer
        __syncthreads();
        for (int off = 1; off < 256; off <<= 1) {
            float v = stage[tid];
            float u = (tid + off < 256) ? stage[tid + off] : 0.f;
            __syncthreads();
            stage[tid] = v + u;
            __syncthreads();
        }
        float run = (tid < 255) ? stage[tid + 1] : 0.f;   // sum s >= (tid+1)*8
#pragma unroll
        for (int k = 7; k >= 0; --k) {
            int t = tid * 8 + k;
            if (t >= t0 && t < t0 + seglen)
                wseg[t - t0] = expf(run);
            run += a[k];
        }
        __syncthreads();   // wseg ready; scan scratch dead
    }

    // ---------------- phase 2: t-dense staged outer-product ---------------------
    const int wave = tid >> 6;
    const int lane = tid & 63;
    const int tg = lane >> 4;       // 0..3 : t within 4-t group
    const int pg = lane & 15;       // 0..15: p-quad

    const float* Xrow = Xg + (((size_t)b * SEQ + t0) * NH + h) * DH;
    const float* Brow = Bg + (((size_t)b * SEQ + t0) * NH + h) * DS;
    const int NTILE = seglen / TT;

    f4 a00 = (f4)0.f, a01 = (f4)0.f, a02 = (f4)0.f, a03 = (f4)0.f;
    f4 a10 = (f4)0.f, a11 = (f4)0.f, a12 = (f4)0.f, a13 = (f4)0.f;
    f4 a20 = (f4)0.f, a21 = (f4)0.f, a22 = (f4)0.f, a23 = (f4)0.f;
    f4 a30 = (f4)0.f, a31 = (f4)0.f, a32 = (f4)0.f, a33 = (f4)0.f;

    int cur = 0;
    stage_tile(Xrow, Brow, stage, 0, wave, lane);
    __syncthreads();   // tile 0 landed (compiler drains vmcnt before barrier)

#pragma unroll 1
    for (int s = 0; s < NTILE; ++s) {
        if (s + 1 < NTILE)
            stage_tile(Xrow, Brow, stage + (cur ^ 1) * BUFF, (s + 1) * TT, wave, lane);

        const float* Xb = stage + cur * BUFF;
        const float* Bb = Xb + XTF;
        const float* wp = wseg + s * TT;
#pragma unroll
        for (int r = 0; r < 2; ++r) {
            const int tl = (wave * 2 + r) * 4 + tg;          // t within tile
            f4 xv = *(const f4*)&Xb[tl * DH + pg * 4];       // 1 stride-1 b128 / 4t
            float wv = wp[tl];
            f4 xw = xv * wv;
            f4 b0 = *(const f4*)&Bb[tl * DS + 0];
            f4 b1 = *(const f4*)&Bb[tl * DS + 4];
            f4 b2 = *(const f4*)&Bb[tl * DS + 8];
            f4 b3 = *(const f4*)&Bb[tl * DS + 12];
            a00 += xw.x * b0; a01 += xw.x * b1; a02 += xw.x * b2; a03 += xw.x * b3;
            a10 += xw.y * b0; a11 += xw.y * b1; a12 += xw.y * b2; a13 += xw.y * b3;
            a20 += xw.z * b0; a21 += xw.z * b1; a22 += xw.z * b2; a23 += xw.z * b3;
            a30 += xw.w * b0; a31 += xw.w * b1; a32 += xw.w * b2; a33 += xw.w * b3;
        }
        __syncthreads();   // next tile landed; cur reads done before re-stage
        cur ^= 1;
    }

    // ---------------- phase 3: tg-butterfly, cross-wave LDS reduce, store --------
    a00 = bfly(a00); a01 = bfly(a01); a02 = bfly(a02); a03 = bfly(a03);
    a10 = bfly(a10); a11 = bfly(a11); a12 = bfly(a12); a13 = bfly(a13);
    a20 = bfly(a20); a21 = bfly(a21); a22 = bfly(a22); a23 = bfly(a23);
    a30 = bfly(a30); a31 = bfly(a31); a32 = bfly(a32); a33 = bfly(a33);

    // each wave writes its reduced tile; lane (tg,pg) stores row p = pg*4+tg
    // (static named-var select); staging dead after final barrier -> red[4][WST]
    float* red = stage;
    {
        float* rw = red + wave * WST + (pg * 4 + tg) * RS;
#define SELSTORE(q, A0, A1, A2, A3)                               \
        {                                                         \
            f4 r01 = (tg & 1) ? A1 : A0;                          \
            f4 r23 = (tg & 1) ? A3 : A2;                          \
            f4 v   = (tg & 2) ? r23 : r01;                        \
            *(f4*)&rw[q * 4] = v;                                 \
        }
        SELSTORE(0, a00, a10, a20, a30)
        SELSTORE(1, a01, a11, a21, a31)
        SELSTORE(2, a02, a12, a22, a32)
        SELSTORE(3, a03, a13, a23, a33)
#undef SELSTORE
    }
    __syncthreads();
    {
        const int e = tid * 4;
        const int r = e >> 4;        // p row
        const int c = e & 15;        // n col base
        const float* rp = red + r * RS + c;
        f4 s0 = *(const f4*)(rp);
        f4 s1 = *(const f4*)(rp + WST);
        f4 s2 = *(const f4*)(rp + 2 * WST);
        f4 s3 = *(const f4*)(rp + 3 * WST);
        f4 sv = (s0 + s1) + (s2 + s3);
        *(f4*)(dst + (size_t)bid * OUTBH + e) = sv;
    }
}

// Sum the NSEG=4 segment partials into the final output.
__global__ __launch_bounds__(256)
void seg_reduce4(const float* __restrict__ part, float* __restrict__ out)
{
    int i = blockIdx.x * 256 + threadIdx.x;
    size_t o = (size_t)i * 4;
    f4 s = (f4)0.f;
#pragma unroll
    for (int g2 = 0; g2 < 4; ++g2)
        s += *(const f4*)(part + (size_t)g2 * NBH * OUTBH + o);
    *(f4*)(out + o) = s;
}

extern "C" void kernel_launch(void* const* d_in, const int* in_sizes, int n_in,
                              void* d_out, int out_size, void* d_ws, size_t ws_size,
                              hipStream_t stream)
{
    const float* X  = (const float*)d_in[0];
    const float* A  = (const float*)d_in[1];
    const float* Bm = (const float*)d_in[2];
    // d_in[3] (C) is unused by the reference output.
    float* out = (float*)d_out;

    const size_t need = (size_t)4 * NBH * OUTBH * sizeof(float);  // 8 MB
    const int nseg   = (d_ws && ws_size >= need) ? 4 : 1;
    const int seglen = SEQ / nseg;
    float* dst = (nseg == 4) ? (float*)d_ws : out;
    const size_t lds = (size_t)(seglen + 2 * BUFF) * sizeof(float);  // 2*BUFF == 4*WST

    ssd_state_tdense<<<dim3(nseg * NBH), dim3(256), lds, stream>>>(X, A, Bm, dst, seglen);
    if (nseg == 4)
        seg_reduce4<<<dim3((NBH * OUTBH) / 1024), dim3(256), 0, stream>>>((const float*)d_ws, out);
}